// Round 1
// baseline (782.013 us; speedup 1.0000x reference)
//
#include <hip/hip_runtime.h>

#define S_LEN 4096
#define DIM   512
#define NH    8
#define HD    64
#define SCALE 0.125f

// XOR-swizzle for [64][64] float LDS tiles: swizzles float4 granules so that
// column-slice reads (16 lanes reading 16 different rows at the same column,
// row stride 64 floats == 0 mod 32 banks) spread across bank quads.
__device__ __forceinline__ int swz(int row, int col) {
  return (row << 6) + ((((col >> 2) ^ (row >> 2)) & 15) << 2) + (col & 3);
}

// C[m][n] = scale * sum_k A[m][k] * W[k][n]
// A: [4096][512] row-major, W: [512][512] row-major, C: [4096][512] row-major.
// 64x64 block tile, 256 threads, 4x4 micro-tile/thread, BK=32.
__global__ __launch_bounds__(256)
void gemm512(const float* __restrict__ A, const float* __restrict__ W,
             float* __restrict__ C, float scale) {
  __shared__ float As[32 * 64];  // transposed: As[k][m]
  __shared__ float Ws[32 * 64];  // Ws[k][n]
  const int tid = threadIdx.x;
  const int m0 = blockIdx.x * 64;
  const int n0 = blockIdx.y * 64;
  const int ty = tid >> 4, tx = tid & 15;

  float acc[4][4] = {};

  for (int k0 = 0; k0 < DIM; k0 += 32) {
    // ---- stage A (transposed) and W tiles ----
    {
      const int r  = tid >> 3;         // 0..31
      const int kq = (tid & 7) << 2;   // 0,4,...,28
#pragma unroll
      for (int p = 0; p < 2; ++p) {
        const int m = r + p * 32;
        const float4 a4 =
            *reinterpret_cast<const float4*>(&A[(m0 + m) * DIM + k0 + kq]);
        As[(kq + 0) * 64 + m] = a4.x;
        As[(kq + 1) * 64 + m] = a4.y;
        As[(kq + 2) * 64 + m] = a4.z;
        As[(kq + 3) * 64 + m] = a4.w;
      }
      const int kr = tid >> 4;         // 0..15
      const int c4 = (tid & 15) << 2;  // 0..60
#pragma unroll
      for (int p = 0; p < 2; ++p) {
        const int k = kr + p * 16;
        *reinterpret_cast<float4*>(&Ws[k * 64 + c4]) =
            *reinterpret_cast<const float4*>(&W[(k0 + k) * DIM + n0 + c4]);
      }
    }
    __syncthreads();

#pragma unroll 8
    for (int kk = 0; kk < 32; ++kk) {
      const float4 a4 = *reinterpret_cast<const float4*>(&As[kk * 64 + ty * 4]);
      const float4 b4 = *reinterpret_cast<const float4*>(&Ws[kk * 64 + tx * 4]);
      const float a[4] = {a4.x, a4.y, a4.z, a4.w};
      const float b[4] = {b4.x, b4.y, b4.z, b4.w};
#pragma unroll
      for (int i = 0; i < 4; ++i)
#pragma unroll
        for (int j = 0; j < 4; ++j)
          acc[i][j] = fmaf(a[i], b[j], acc[i][j]);
    }
    __syncthreads();
  }

#pragma unroll
  for (int i = 0; i < 4; ++i) {
    float4 o4;
    o4.x = acc[i][0] * scale;
    o4.y = acc[i][1] * scale;
    o4.z = acc[i][2] * scale;
    o4.w = acc[i][3] * scale;
    *reinterpret_cast<float4*>(&C[(m0 + ty * 4 + i) * DIM + n0 + tx * 4]) = o4;
  }
}

// Flash attention, fp32. One block = (head h, 64 query rows).
// Q/K/V: [4096][512] with head h at columns h*64..h*64+63 (q pre-scaled).
// O: same layout.
__global__ __launch_bounds__(256)
void attn_fwd(const float* __restrict__ Q, const float* __restrict__ K,
              const float* __restrict__ V, float* __restrict__ O) {
  __shared__ float Qs[64 * 64];
  __shared__ float Ks[64 * 64];
  __shared__ float Vs[64 * 64];
  __shared__ float Pt[64 * 64];  // P transposed: Pt[kcol][qrow]

  const int tid = threadIdx.x;
  const int h  = blockIdx.y;
  const int q0 = blockIdx.x * 64;
  const int ty = tid >> 4, tx = tid & 15;
  const int lr = tid >> 4;          // load row base 0..15
  const int lc = (tid & 15) << 2;   // load col 0..60

  // stage Q tile once
#pragma unroll
  for (int p = 0; p < 4; ++p) {
    const int r = lr + p * 16;
    *reinterpret_cast<float4*>(&Qs[swz(r, lc)]) =
        *reinterpret_cast<const float4*>(&Q[(q0 + r) * DIM + h * HD + lc]);
  }

  float m_i[4], l_i[4], o_acc[4][4];
#pragma unroll
  for (int i = 0; i < 4; ++i) {
    m_i[i] = -1e30f;
    l_i[i] = 0.f;
#pragma unroll
    for (int j = 0; j < 4; ++j) o_acc[i][j] = 0.f;
  }

  for (int t0 = 0; t0 < S_LEN; t0 += 64) {
    __syncthreads();  // prev PV (and Q staging on iter 0) complete
#pragma unroll
    for (int p = 0; p < 4; ++p) {
      const int r = lr + p * 16;
      *reinterpret_cast<float4*>(&Ks[swz(r, lc)]) =
          *reinterpret_cast<const float4*>(&K[(t0 + r) * DIM + h * HD + lc]);
      *reinterpret_cast<float4*>(&Vs[swz(r, lc)]) =
          *reinterpret_cast<const float4*>(&V[(t0 + r) * DIM + h * HD + lc]);
    }
    __syncthreads();

    // ---- scores: s[i][j] = sum_d Q[ty*4+i][d] * K[tx*4+j][d] ----
    float s[4][4] = {};
#pragma unroll 4
    for (int dd = 0; dd < HD; dd += 4) {
      float4 qv[4], kv[4];
#pragma unroll
      for (int i = 0; i < 4; ++i)
        qv[i] = *reinterpret_cast<const float4*>(&Qs[swz(ty * 4 + i, dd)]);
#pragma unroll
      for (int j = 0; j < 4; ++j)
        kv[j] = *reinterpret_cast<const float4*>(&Ks[swz(tx * 4 + j, dd)]);
#pragma unroll
      for (int i = 0; i < 4; ++i)
#pragma unroll
        for (int j = 0; j < 4; ++j) {
          s[i][j] = fmaf(qv[i].x, kv[j].x, s[i][j]);
          s[i][j] = fmaf(qv[i].y, kv[j].y, s[i][j]);
          s[i][j] = fmaf(qv[i].z, kv[j].z, s[i][j]);
          s[i][j] = fmaf(qv[i].w, kv[j].w, s[i][j]);
        }
    }

    // ---- online softmax (row reduce across the 16 tx lanes) ----
#pragma unroll
    for (int i = 0; i < 4; ++i) {
      float mx = fmaxf(fmaxf(s[i][0], s[i][1]), fmaxf(s[i][2], s[i][3]));
#pragma unroll
      for (int off = 1; off < 16; off <<= 1)
        mx = fmaxf(mx, __shfl_xor(mx, off, 64));
      const float mn = fmaxf(m_i[i], mx);
      const float alpha = __expf(m_i[i] - mn);
      m_i[i] = mn;
      float rs = 0.f;
#pragma unroll
      for (int j = 0; j < 4; ++j) {
        s[i][j] = __expf(s[i][j] - mn);
        rs += s[i][j];
      }
#pragma unroll
      for (int off = 1; off < 16; off <<= 1)
        rs += __shfl_xor(rs, off, 64);
      l_i[i] = l_i[i] * alpha + rs;
#pragma unroll
      for (int j = 0; j < 4; ++j) o_acc[i][j] *= alpha;
    }

    // ---- write P transposed (float4 along qrow) ----
#pragma unroll
    for (int j = 0; j < 4; ++j) {
      const float4 p4 = make_float4(s[0][j], s[1][j], s[2][j], s[3][j]);
      *reinterpret_cast<float4*>(&Pt[swz(tx * 4 + j, ty * 4)]) = p4;
    }
    __syncthreads();

    // ---- O += P * V ----
#pragma unroll 8
    for (int kk = 0; kk < 64; ++kk) {
      const float4 pa = *reinterpret_cast<const float4*>(&Pt[swz(kk, ty * 4)]);
      const float4 vb = *reinterpret_cast<const float4*>(&Vs[swz(kk, tx * 4)]);
      const float a[4] = {pa.x, pa.y, pa.z, pa.w};
      const float b[4] = {vb.x, vb.y, vb.z, vb.w};
#pragma unroll
      for (int i = 0; i < 4; ++i)
#pragma unroll
        for (int j = 0; j < 4; ++j)
          o_acc[i][j] = fmaf(a[i], b[j], o_acc[i][j]);
    }
  }

  // ---- finalize: divide by row sum, store ----
#pragma unroll
  for (int i = 0; i < 4; ++i) {
    const float inv = 1.f / l_i[i];
    float4 o4;
    o4.x = o_acc[i][0] * inv;
    o4.y = o_acc[i][1] * inv;
    o4.z = o_acc[i][2] * inv;
    o4.w = o_acc[i][3] * inv;
    *reinterpret_cast<float4*>(&O[(q0 + ty * 4 + i) * DIM + h * HD + tx * 4]) = o4;
  }
}

extern "C" void kernel_launch(void* const* d_in, const int* in_sizes, int n_in,
                              void* d_out, int out_size, void* d_ws, size_t ws_size,
                              hipStream_t stream) {
  const float* x  = (const float*)d_in[0];  // [4096][512]
  const float* qp = (const float*)d_in[1];  // [512][8][64] == [512][512]
  const float* kp = (const float*)d_in[2];
  const float* vp = (const float*)d_in[3];
  const float* pp = (const float*)d_in[4];  // [8][64][512] == [512][512]
  float* out = (float*)d_out;               // [4096][512]

  float* q = (float*)d_ws;                  // [4096][512] each, 8 MB each
  float* k = q + S_LEN * DIM;
  float* v = k + S_LEN * DIM;
  float* o = v + S_LEN * DIM;

  const dim3 blk(256);
  const dim3 gg(S_LEN / 64, DIM / 64);  // 64 x 8

  gemm512<<<gg, blk, 0, stream>>>(x, qp, q, SCALE);
  gemm512<<<gg, blk, 0, stream>>>(x, kp, k, 1.0f);
  gemm512<<<gg, blk, 0, stream>>>(x, vp, v, 1.0f);
  attn_fwd<<<dim3(S_LEN / 64, NH), blk, 0, stream>>>(q, k, v, o);
  gemm512<<<gg, blk, 0, stream>>>(o, pp, out, 1.0f);
}

// Round 2
// 303.588 us; speedup vs baseline: 2.5759x; 2.5759x over previous
//
#include <hip/hip_runtime.h>
#include <stdint.h>

#define S_LEN 4096
#define DIM   512
#define NH    8
#define HD    64
// 0.125 * log2(e): fold softmax base-2 conversion into the Q projection
#define QSCALE 0.18033688011112042f

typedef __attribute__((ext_vector_type(8))) short short8;
typedef __attribute__((ext_vector_type(4))) float f32x4;

__device__ __forceinline__ uint32_t f2bf(float x) {
  union { float f; uint32_t u; } v; v.f = x;
  return (v.u + 0x7FFFu + ((v.u >> 16) & 1u)) >> 16;  // RNE to bf16 bits
}
__device__ __forceinline__ uint32_t pk2(float lo, float hi) {
  return f2bf(lo) | (f2bf(hi) << 16);
}

// ---------------- fp32 GEMM (unchanged from R1) ----------------
__global__ __launch_bounds__(256)
void gemm512(const float* __restrict__ A, const float* __restrict__ W,
             float* __restrict__ C, float scale) {
  __shared__ float As[32 * 64];
  __shared__ float Ws[32 * 64];
  const int tid = threadIdx.x;
  const int m0 = blockIdx.x * 64;
  const int n0 = blockIdx.y * 64;
  const int ty = tid >> 4, tx = tid & 15;

  float acc[4][4] = {};

  for (int k0 = 0; k0 < DIM; k0 += 32) {
    {
      const int r  = tid >> 3;
      const int kq = (tid & 7) << 2;
#pragma unroll
      for (int p = 0; p < 2; ++p) {
        const int m = r + p * 32;
        const float4 a4 =
            *reinterpret_cast<const float4*>(&A[(m0 + m) * DIM + k0 + kq]);
        As[(kq + 0) * 64 + m] = a4.x;
        As[(kq + 1) * 64 + m] = a4.y;
        As[(kq + 2) * 64 + m] = a4.z;
        As[(kq + 3) * 64 + m] = a4.w;
      }
      const int kr = tid >> 4;
      const int c4 = (tid & 15) << 2;
#pragma unroll
      for (int p = 0; p < 2; ++p) {
        const int k = kr + p * 16;
        *reinterpret_cast<float4*>(&Ws[k * 64 + c4]) =
            *reinterpret_cast<const float4*>(&W[(k0 + k) * DIM + n0 + c4]);
      }
    }
    __syncthreads();

#pragma unroll 8
    for (int kk = 0; kk < 32; ++kk) {
      const float4 a4 = *reinterpret_cast<const float4*>(&As[kk * 64 + ty * 4]);
      const float4 b4 = *reinterpret_cast<const float4*>(&Ws[kk * 64 + tx * 4]);
      const float a[4] = {a4.x, a4.y, a4.z, a4.w};
      const float b[4] = {b4.x, b4.y, b4.z, b4.w};
#pragma unroll
      for (int i = 0; i < 4; ++i)
#pragma unroll
        for (int j = 0; j < 4; ++j)
          acc[i][j] = fmaf(a[i], b[j], acc[i][j]);
    }
    __syncthreads();
  }

#pragma unroll
  for (int i = 0; i < 4; ++i) {
    float4 o4;
    o4.x = acc[i][0] * scale;
    o4.y = acc[i][1] * scale;
    o4.z = acc[i][2] * scale;
    o4.w = acc[i][3] * scale;
    *reinterpret_cast<float4*>(&C[(m0 + ty * 4 + i) * DIM + n0 + tx * 4]) = o4;
  }
}

// ---------------- MFMA flash attention (swapped QK^T, bf16) ----------------
// Block: 256 threads = 4 waves; wave w owns q-rows q0+16w..+15 of head h.
// Per KV tile (64 rows): S^T = K_tile * Q^T via mfma(K-frag, Q-frag);
// lane owns q-col = lane&15, kpos = 16t + 4*(lane>>4) + reg.
// LDS (swizzled byte ^= (row&7)<<4):
//   [0,8K)    Ks : bf16 [64 kpos][64 d] row-major
//   [8K,16K)  Vt : bf16 [64 d][64 kpos] (V transposed)
//   [16K,24K) P  : per-wave 2KB, bf16 [16 q][64 kpos]  (wave-private, no barrier)
__global__ __launch_bounds__(256)
void attn_mfma(const float* __restrict__ Q, const float* __restrict__ K,
               const float* __restrict__ V, float* __restrict__ O) {
  __shared__ __align__(16) unsigned char lds[24576];

  const int tid  = threadIdx.x;
  const int h    = blockIdx.y;
  const int q0   = blockIdx.x * 64;
  const int lane = tid & 63;
  const int w    = tid >> 6;
  const int g    = lane >> 4;
  const int q    = lane & 15;
  const int qsw  = (q & 7) << 4;

  // Q fragments (B-operand): lane holds Q[q][c*32 + g*8 + i]
  short8 qf[2];
  {
    const float* qp = &Q[(q0 + w * 16 + q) * DIM + h * HD + g * 8];
#pragma unroll
    for (int c = 0; c < 2; ++c) {
      const float4 f0 = *reinterpret_cast<const float4*>(qp + c * 32);
      const float4 f1 = *reinterpret_cast<const float4*>(qp + c * 32 + 4);
      uint32_t u[4] = {pk2(f0.x, f0.y), pk2(f0.z, f0.w),
                       pk2(f1.x, f1.y), pk2(f1.z, f1.w)};
      qf[c] = *reinterpret_cast<short8*>(u);
    }
  }

  f32x4 o[4] = {};
  float m_i = -1e30f, l_i = 0.f;

  // staging assignments
  const int kr = tid >> 2, kq = tid & 3;          // K: row, 16-float quarter
  const int vpair = tid >> 3, vdq = tid & 7;      // V: kpos row-pair, d-quad

  for (int kv0 = 0; kv0 < S_LEN; kv0 += 64) {
    // ---- global loads issued before the barrier (overlap prev compute) ----
    const float* kgp = &K[(kv0 + kr) * DIM + h * HD + kq * 16];
    const float4 k0 = *reinterpret_cast<const float4*>(kgp + 0);
    const float4 k1 = *reinterpret_cast<const float4*>(kgp + 4);
    const float4 k2 = *reinterpret_cast<const float4*>(kgp + 8);
    const float4 k3 = *reinterpret_cast<const float4*>(kgp + 12);
    const float* vgp = &V[(kv0 + 2 * vpair) * DIM + h * HD];
    const float4 va0 = *reinterpret_cast<const float4*>(vgp + vdq * 4);
    const float4 va1 = *reinterpret_cast<const float4*>(vgp + DIM + vdq * 4);
    const float4 vb0 = *reinterpret_cast<const float4*>(vgp + vdq * 4 + 32);
    const float4 vb1 = *reinterpret_cast<const float4*>(vgp + DIM + vdq * 4 + 32);

    __syncthreads();  // previous tile's LDS reads complete

    {  // K tile -> bf16, row-major, swizzled
      uint4 w0, w1;
      w0.x = pk2(k0.x, k0.y); w0.y = pk2(k0.z, k0.w);
      w0.z = pk2(k1.x, k1.y); w0.w = pk2(k1.z, k1.w);
      w1.x = pk2(k2.x, k2.y); w1.y = pk2(k2.z, k2.w);
      w1.z = pk2(k3.x, k3.y); w1.w = pk2(k3.z, k3.w);
      unsigned char* kb = lds + kr * 128;
      const int ksw = (kr & 7) << 4;
      *reinterpret_cast<uint4*>(kb + ((kq * 32) ^ ksw))      = w0;
      *reinterpret_cast<uint4*>(kb + ((kq * 32 + 16) ^ ksw)) = w1;
    }
    {  // V tile -> bf16 transposed Vt[d][kpos], swizzled
      const float* a0 = reinterpret_cast<const float*>(&va0);
      const float* a1 = reinterpret_cast<const float*>(&va1);
      const float* b0 = reinterpret_cast<const float*>(&vb0);
      const float* b1 = reinterpret_cast<const float*>(&vb1);
#pragma unroll
      for (int j = 0; j < 4; ++j) {
        const int d1 = 4 * vdq + j;
        const int d2 = d1 + 32;
        *reinterpret_cast<uint32_t*>(
            lds + 8192 + d1 * 128 + ((4 * vpair) ^ ((d1 & 7) << 4))) =
            pk2(a0[j], a1[j]);
        *reinterpret_cast<uint32_t*>(
            lds + 8192 + d2 * 128 + ((4 * vpair) ^ ((d2 & 7) << 4))) =
            pk2(b0[j], b1[j]);
      }
    }
    __syncthreads();

    // ---- S^T = K * Q^T : lane -> q-col (lane&15), kpos = 16t+4g+reg ----
    f32x4 s[4] = {};
#pragma unroll
    for (int t = 0; t < 4; ++t)
#pragma unroll
      for (int c = 0; c < 2; ++c) {
        const short8 af = *reinterpret_cast<const short8*>(
            lds + (16 * t + q) * 128 + ((64 * c + 16 * g) ^ qsw));
        s[t] = __builtin_amdgcn_mfma_f32_16x16x32_bf16(af, qf[c], s[t], 0, 0, 0);
      }

    // ---- online softmax (base-2; scale folded into Q) ----
    float mx = s[0][0];
#pragma unroll
    for (int t = 0; t < 4; ++t)
#pragma unroll
      for (int r = 0; r < 4; ++r) mx = fmaxf(mx, s[t][r]);
    mx = fmaxf(mx, __shfl_xor(mx, 16));
    mx = fmaxf(mx, __shfl_xor(mx, 32));
    const float mnew = fmaxf(m_i, mx);
    float rs = 0.f;
#pragma unroll
    for (int t = 0; t < 4; ++t)
#pragma unroll
      for (int r = 0; r < 4; ++r) {
        const float p = exp2f(s[t][r] - mnew);
        s[t][r] = p;
        rs += p;
      }
    rs += __shfl_xor(rs, 16);
    rs += __shfl_xor(rs, 32);
    const bool grow  = mnew > m_i;
    const float alpha = grow ? exp2f(m_i - mnew) : 1.0f;
    l_i = l_i * alpha + rs;
    m_i = mnew;
    if (__any(grow)) {
#pragma unroll
      for (int r = 0; r < 4; ++r) {
        const float ar = __shfl(alpha, 4 * g + r);
#pragma unroll
        for (int dt = 0; dt < 4; ++dt) o[dt][r] *= ar;
      }
    }

    // ---- P -> wave-private LDS (bf16), reload as PV A-fragments ----
    unsigned char* pb = lds + 16384 + w * 2048 + q * 128;
#pragma unroll
    for (int t = 0; t < 4; ++t) {
      uint2 pw;
      pw.x = pk2(s[t][0], s[t][1]);
      pw.y = pk2(s[t][2], s[t][3]);
      *reinterpret_cast<uint2*>(pb + ((32 * t + 8 * g) ^ qsw)) = pw;
    }
    short8 pa[2];
#pragma unroll
    for (int c = 0; c < 2; ++c)
      pa[c] = *reinterpret_cast<const short8*>(pb + ((64 * c + 16 * g) ^ qsw));

    // ---- O += P * V ----
#pragma unroll
    for (int dt = 0; dt < 4; ++dt)
#pragma unroll
      for (int c = 0; c < 2; ++c) {
        const short8 vf = *reinterpret_cast<const short8*>(
            lds + 8192 + (16 * dt + q) * 128 + ((64 * c + 16 * g) ^ qsw));
        o[dt] = __builtin_amdgcn_mfma_f32_16x16x32_bf16(pa[c], vf, o[dt], 0, 0, 0);
      }
  }

  // ---- epilogue: divide by l, store ----
#pragma unroll
  for (int r = 0; r < 4; ++r) {
    const float linv = 1.0f / __shfl(l_i, 4 * g + r);
    const int row = q0 + w * 16 + 4 * g + r;
#pragma unroll
    for (int dt = 0; dt < 4; ++dt)
      O[row * DIM + h * HD + 16 * dt + q] = o[dt][r] * linv;
  }
}

extern "C" void kernel_launch(void* const* d_in, const int* in_sizes, int n_in,
                              void* d_out, int out_size, void* d_ws, size_t ws_size,
                              hipStream_t stream) {
  const float* x  = (const float*)d_in[0];
  const float* qp = (const float*)d_in[1];
  const float* kp = (const float*)d_in[2];
  const float* vp = (const float*)d_in[3];
  const float* pp = (const float*)d_in[4];
  float* out = (float*)d_out;

  float* q = (float*)d_ws;
  float* k = q + S_LEN * DIM;
  float* v = k + S_LEN * DIM;
  float* o = v + S_LEN * DIM;

  const dim3 blk(256);
  const dim3 gg(S_LEN / 64, DIM / 64);

  gemm512<<<gg, blk, 0, stream>>>(x, qp, q, QSCALE);
  gemm512<<<gg, blk, 0, stream>>>(x, kp, k, 1.0f);
  gemm512<<<gg, blk, 0, stream>>>(x, vp, v, 1.0f);
  attn_mfma<<<dim3(S_LEN / 64, NH), blk, 0, stream>>>(q, k, v, o);
  gemm512<<<gg, blk, 0, stream>>>(o, pp, out, 1.0f);
}

// Round 3
// 135.085 us; speedup vs baseline: 5.7891x; 2.2474x over previous
//
#include <hip/hip_runtime.h>
#include <hip/hip_bf16.h>
#include <stdint.h>

#define S_LEN 4096
#define DIM   512
#define NH    8
#define HD    64
// 0.125 * log2(e): fold softmax base-2 conversion into the Q projection weights
#define QSCALE 0.18033688011112042f

typedef __attribute__((ext_vector_type(8))) short short8;
typedef __attribute__((ext_vector_type(4))) float f32x4;

__device__ __forceinline__ uint32_t pk2(float lo, float hi) {
  union { __hip_bfloat162 h; uint32_t u; } cv;
  cv.h = __float22bfloat162_rn(float2{lo, hi});
  return cv.u;
}
__device__ __forceinline__ ushort bf1(float x) {
  union { __hip_bfloat16 b; ushort u; } cv;
  cv.b = __float2bfloat16(x);
  return cv.u;
}

// ---------------- prep: x -> bf16 ----------------
__global__ __launch_bounds__(256)
void cast_x(const float* __restrict__ src, ushort* __restrict__ dst) {
  const int i = (blockIdx.x * 256 + threadIdx.x) * 8;
  const float4 a = *reinterpret_cast<const float4*>(src + i);
  const float4 b = *reinterpret_cast<const float4*>(src + i + 4);
  uint4 o;
  o.x = pk2(a.x, a.y); o.y = pk2(a.z, a.w);
  o.z = pk2(b.x, b.y); o.w = pk2(b.z, b.w);
  *reinterpret_cast<uint4*>(dst + i) = o;
}

// ---------------- prep: transpose weights to bf16 ----------------
// z=0..2: wbT[z*512 + n][k] = {qp,kp,vp}[k][n] (*QSCALE for z=0)
// z=3   : ppT[n][k] = pp[k][n]
__global__ __launch_bounds__(256)
void transpose_w(const float* __restrict__ qp, const float* __restrict__ kp,
                 const float* __restrict__ vp, const float* __restrict__ pp,
                 ushort* __restrict__ wbT, ushort* __restrict__ ppT) {
  __shared__ float L[64][65];
  const int z = blockIdx.z;
  const float* src = (z == 0) ? qp : (z == 1) ? kp : (z == 2) ? vp : pp;
  ushort* dst = (z < 3) ? (wbT + (size_t)z * 512 * 512) : ppT;
  const float scale = (z == 0) ? QSCALE : 1.0f;
  const int k0 = blockIdx.x * 64, n0 = blockIdx.y * 64;
  const int r = threadIdx.x >> 2, c0 = (threadIdx.x & 3) * 16;

#pragma unroll
  for (int j = 0; j < 4; ++j) {
    const float4 v =
        *reinterpret_cast<const float4*>(&src[(k0 + r) * 512 + n0 + c0 + 4 * j]);
    L[r][c0 + 4 * j + 0] = v.x * scale;
    L[r][c0 + 4 * j + 1] = v.y * scale;
    L[r][c0 + 4 * j + 2] = v.z * scale;
    L[r][c0 + 4 * j + 3] = v.w * scale;
  }
  __syncthreads();

  uint4 u0, u1;
  u0.x = pk2(L[c0 + 0][r], L[c0 + 1][r]);
  u0.y = pk2(L[c0 + 2][r], L[c0 + 3][r]);
  u0.z = pk2(L[c0 + 4][r], L[c0 + 5][r]);
  u0.w = pk2(L[c0 + 6][r], L[c0 + 7][r]);
  u1.x = pk2(L[c0 + 8][r], L[c0 + 9][r]);
  u1.y = pk2(L[c0 + 10][r], L[c0 + 11][r]);
  u1.z = pk2(L[c0 + 12][r], L[c0 + 13][r]);
  u1.w = pk2(L[c0 + 14][r], L[c0 + 15][r]);
  ushort* d = dst + (size_t)(n0 + r) * 512 + k0 + c0;
  *reinterpret_cast<uint4*>(d) = u0;
  *reinterpret_cast<uint4*>(d + 8) = u1;
}

// ---------------- bf16 MFMA GEMM ----------------
// A: [M][512] bf16 row-major. Bt: [N][512] bf16 (pre-transposed). BM=128 BN=64 BK=64.
// 4 waves in 2x2; wave tile 64x32 = 4x2 fragments of 16x16.
// MODE 0: write bf16 to qkv[3][8][4096][64] head-major. MODE 1: write f32 [M][512].
template <int MODE>
__global__ __launch_bounds__(256)
void gemm_bf16(const ushort* __restrict__ A, const ushort* __restrict__ Bt,
               void* __restrict__ Cout) {
  __shared__ __align__(16) unsigned char lds[24576];  // As 16K | Bs 8K
  const int tid = threadIdx.x;
  const int m0 = blockIdx.x * 128, n0 = blockIdx.y * 64;
  const int lane = tid & 63, w = tid >> 6;
  const int wm = w >> 1, wn = w & 1;
  const int q = lane & 15, g = lane >> 4;
  f32x4 acc[4][2] = {};

  const int ar = tid >> 1, ah = tid & 1;  // A stage: row, 64B half
  const int br = tid >> 2, bq = tid & 3;  // B stage: row, 32B quarter

  for (int k0 = 0; k0 < 512; k0 += 64) {
    const ushort* ag = A + (size_t)(m0 + ar) * 512 + k0 + ah * 32;
    const uint4 a0 = *reinterpret_cast<const uint4*>(ag);
    const uint4 a1 = *reinterpret_cast<const uint4*>(ag + 8);
    const uint4 a2 = *reinterpret_cast<const uint4*>(ag + 16);
    const uint4 a3 = *reinterpret_cast<const uint4*>(ag + 24);
    const ushort* bg = Bt + (size_t)(n0 + br) * 512 + k0 + bq * 16;
    const uint4 b0 = *reinterpret_cast<const uint4*>(bg);
    const uint4 b1 = *reinterpret_cast<const uint4*>(bg + 8);
    __syncthreads();
    {
      unsigned char* ab = lds + ar * 128;
      const int asw = (ar & 7) << 4;
      *reinterpret_cast<uint4*>(ab + ((ah * 64 + 0) ^ asw)) = a0;
      *reinterpret_cast<uint4*>(ab + ((ah * 64 + 16) ^ asw)) = a1;
      *reinterpret_cast<uint4*>(ab + ((ah * 64 + 32) ^ asw)) = a2;
      *reinterpret_cast<uint4*>(ab + ((ah * 64 + 48) ^ asw)) = a3;
      unsigned char* bb = lds + 16384 + br * 128;
      const int bsw = (br & 7) << 4;
      *reinterpret_cast<uint4*>(bb + ((bq * 32 + 0) ^ bsw)) = b0;
      *reinterpret_cast<uint4*>(bb + ((bq * 32 + 16) ^ bsw)) = b1;
    }
    __syncthreads();

#pragma unroll
    for (int ks = 0; ks < 2; ++ks) {
      short8 bf[2];
#pragma unroll
      for (int ni = 0; ni < 2; ++ni) {
        const int rn = wn * 32 + ni * 16 + q;
        bf[ni] = *reinterpret_cast<const short8*>(
            lds + 16384 + rn * 128 + ((64 * ks + 16 * g) ^ ((rn & 7) << 4)));
      }
#pragma unroll
      for (int mi = 0; mi < 4; ++mi) {
        const int rm = wm * 64 + mi * 16 + q;
        const short8 af = *reinterpret_cast<const short8*>(
            lds + rm * 128 + ((64 * ks + 16 * g) ^ ((rm & 7) << 4)));
#pragma unroll
        for (int ni = 0; ni < 2; ++ni)
          acc[mi][ni] = __builtin_amdgcn_mfma_f32_16x16x32_bf16(
              af, bf[ni], acc[mi][ni], 0, 0, 0);
      }
    }
  }

  if (MODE == 0) {
    ushort* C = (ushort*)Cout;
#pragma unroll
    for (int ni = 0; ni < 2; ++ni) {
      const int n = n0 + wn * 32 + ni * 16 + q;
      const int which = n >> 9, rem = n & 511, h = rem >> 6, d = rem & 63;
      ushort* base = C + ((size_t)which * NH + h) * (size_t)(S_LEN * HD) + d;
#pragma unroll
      for (int mi = 0; mi < 4; ++mi) {
        const int s = m0 + wm * 64 + mi * 16 + 4 * g;
#pragma unroll
        for (int r = 0; r < 4; ++r)
          base[(size_t)(s + r) * HD] = bf1(acc[mi][ni][r]);
      }
    }
  } else {
    float* C = (float*)Cout;
#pragma unroll
    for (int ni = 0; ni < 2; ++ni) {
      const int n = n0 + wn * 32 + ni * 16 + q;
#pragma unroll
      for (int mi = 0; mi < 4; ++mi) {
        const int s = m0 + wm * 64 + mi * 16 + 4 * g;
#pragma unroll
        for (int r = 0; r < 4; ++r)
          C[(size_t)(s + r) * 512 + n] = acc[mi][ni][r];
      }
    }
  }
}

// ---------------- MFMA flash attention, bf16 inputs ----------------
// QKV: [3][8][4096][64] bf16 head-major. Ob: [4096][512] bf16.
// LDS: [0,8K) K [64 kpos][64 d] swz ((row&7)<<4); [8K,16K) Vt [64 d][64 kpos]
// swz (((d>>3)&3)<<5); [16K,24K) P per-wave 2KB [16 q][64 kpos] swz ((q&7)<<4).
__global__ __launch_bounds__(256)
void attn_mfma(const ushort* __restrict__ QKV, ushort* __restrict__ Ob) {
  __shared__ __align__(16) unsigned char lds[24576];
  const int tid = threadIdx.x;
  const int h = blockIdx.y, q0 = blockIdx.x * 64;
  const int lane = tid & 63, w = tid >> 6;
  const int g = lane >> 4, q = lane & 15;
  const int qsw = (q & 7) << 4;
  const size_t plane = (size_t)S_LEN * HD;
  const ushort* Qp = QKV + (size_t)h * plane;
  const ushort* Kp = QKV + (size_t)(NH + h) * plane;
  const ushort* Vp = QKV + (size_t)(2 * NH + h) * plane;

  short8 qf[2];
  {
    const ushort* qptr = Qp + (size_t)(q0 + w * 16 + q) * HD + 8 * g;
    qf[0] = *reinterpret_cast<const short8*>(qptr);
    qf[1] = *reinterpret_cast<const short8*>(qptr + 32);
  }

  f32x4 o[4] = {};
  float m_i = -1e30f, l_i = 0.f;

  const int kr = tid >> 2, kq = tid & 3;    // K stage: row, 32B quarter
  const int vp2 = tid >> 3, vd = tid & 7;   // V stage: kpos pair, d-octet

  for (int kv0 = 0; kv0 < S_LEN; kv0 += 64) {
    const ushort* kg = Kp + (size_t)(kv0 + kr) * HD + kq * 16;
    const uint4 kd0 = *reinterpret_cast<const uint4*>(kg);
    const uint4 kd1 = *reinterpret_cast<const uint4*>(kg + 8);
    const ushort* vg = Vp + (size_t)(kv0 + 2 * vp2) * HD + vd * 8;
    const uint4 va = *reinterpret_cast<const uint4*>(vg);
    const uint4 vb = *reinterpret_cast<const uint4*>(vg + HD);

    __syncthreads();  // previous tile's LDS reads complete
    {
      unsigned char* kb = lds + kr * 128;
      const int ksw = (kr & 7) << 4;
      *reinterpret_cast<uint4*>(kb + ((kq * 32) ^ ksw)) = kd0;
      *reinterpret_cast<uint4*>(kb + ((kq * 32 + 16) ^ ksw)) = kd1;
    }
    {
      const ushort* ua = reinterpret_cast<const ushort*>(&va);
      const ushort* ub = reinterpret_cast<const ushort*>(&vb);
#pragma unroll
      for (int j = 0; j < 8; ++j) {
        const int d = 8 * vd + j;
        *reinterpret_cast<uint32_t*>(lds + 8192 + d * 128 +
                                     ((4 * vp2) ^ (((d >> 3) & 3) << 5))) =
            (uint32_t)ua[j] | ((uint32_t)ub[j] << 16);
      }
    }
    __syncthreads();

    // ---- S^T = K * Q^T ----
    f32x4 s[4] = {};
#pragma unroll
    for (int t = 0; t < 4; ++t)
#pragma unroll
      for (int c = 0; c < 2; ++c) {
        const short8 af = *reinterpret_cast<const short8*>(
            lds + (16 * t + q) * 128 + ((64 * c + 16 * g) ^ qsw));
        s[t] = __builtin_amdgcn_mfma_f32_16x16x32_bf16(af, qf[c], s[t], 0, 0, 0);
      }

    // ---- online softmax (base 2) ----
    float mx = s[0][0];
#pragma unroll
    for (int t = 0; t < 4; ++t)
#pragma unroll
      for (int r = 0; r < 4; ++r) mx = fmaxf(mx, s[t][r]);
    mx = fmaxf(mx, __shfl_xor(mx, 16));
    mx = fmaxf(mx, __shfl_xor(mx, 32));
    const float mnew = fmaxf(m_i, mx);
    float rs = 0.f;
#pragma unroll
    for (int t = 0; t < 4; ++t)
#pragma unroll
      for (int r = 0; r < 4; ++r) {
        const float p = exp2f(s[t][r] - mnew);
        s[t][r] = p;
        rs += p;
      }
    rs += __shfl_xor(rs, 16);
    rs += __shfl_xor(rs, 32);
    const bool grow = mnew > m_i;
    const float alpha = grow ? exp2f(m_i - mnew) : 1.0f;
    l_i = l_i * alpha + rs;
    m_i = mnew;
    if (__any(grow)) {
#pragma unroll
      for (int r = 0; r < 4; ++r) {
        const float ar = __shfl(alpha, 4 * g + r);
#pragma unroll
        for (int dt = 0; dt < 4; ++dt) o[dt][r] *= ar;
      }
    }

    // ---- P -> wave-private LDS (bf16), reload as PV A-fragments ----
    unsigned char* pb = lds + 16384 + w * 2048 + q * 128;
#pragma unroll
    for (int t = 0; t < 4; ++t) {
      uint2 pw;
      pw.x = pk2(s[t][0], s[t][1]);
      pw.y = pk2(s[t][2], s[t][3]);
      *reinterpret_cast<uint2*>(pb + ((32 * t + 8 * g) ^ qsw)) = pw;
    }
    short8 pa[2];
#pragma unroll
    for (int c = 0; c < 2; ++c)
      pa[c] = *reinterpret_cast<const short8*>(pb + ((64 * c + 16 * g) ^ qsw));

    // ---- O += P * V ----
#pragma unroll
    for (int dt = 0; dt < 4; ++dt) {
      const int vr = 16 * dt + q;
      const int vsw = ((vr >> 3) & 3) << 5;
#pragma unroll
      for (int c = 0; c < 2; ++c) {
        const short8 vf = *reinterpret_cast<const short8*>(
            lds + 8192 + vr * 128 + ((64 * c + 16 * g) ^ vsw));
        o[dt] = __builtin_amdgcn_mfma_f32_16x16x32_bf16(pa[c], vf, o[dt], 0, 0, 0);
      }
    }
  }

  // ---- epilogue ----
#pragma unroll
  for (int r = 0; r < 4; ++r) {
    const float linv = 1.0f / __shfl(l_i, 4 * g + r);
    const int row = q0 + w * 16 + 4 * g + r;
#pragma unroll
    for (int dt = 0; dt < 4; ++dt)
      Ob[(size_t)row * DIM + h * HD + 16 * dt + q] = bf1(o[dt][r] * linv);
  }
}

extern "C" void kernel_launch(void* const* d_in, const int* in_sizes, int n_in,
                              void* d_out, int out_size, void* d_ws, size_t ws_size,
                              hipStream_t stream) {
  const float* x  = (const float*)d_in[0];
  const float* qp = (const float*)d_in[1];
  const float* kp = (const float*)d_in[2];
  const float* vp = (const float*)d_in[3];
  const float* pp = (const float*)d_in[4];
  float* out = (float*)d_out;

  unsigned char* ws = (unsigned char*)d_ws;
  ushort* xb   = (ushort*)(ws);                       // 4 MB  [4096][512]
  ushort* qkvb = (ushort*)(ws + ((size_t)4 << 20));   // 12 MB [3][8][4096][64]
  ushort* ob   = (ushort*)(ws + ((size_t)16 << 20));  // 4 MB  [4096][512]
  ushort* wbT  = (ushort*)(ws + ((size_t)20 << 20));  // 1.5 MB [1536][512]
  ushort* ppT  = (ushort*)(ws + ((size_t)22 << 20));  // 0.5 MB [512][512]

  cast_x<<<dim3(1024), dim3(256), 0, stream>>>(x, xb);
  transpose_w<<<dim3(8, 8, 4), dim3(256), 0, stream>>>(qp, kp, vp, pp, wbT, ppT);
  gemm_bf16<0><<<dim3(32, 24), dim3(256), 0, stream>>>(xb, wbT, qkvb);
  attn_mfma<<<dim3(64, NH), dim3(256), 0, stream>>>(qkvb, ob);
  gemm_bf16<1><<<dim3(32, 8), dim3(256), 0, stream>>>(ob, ppT, out);
}

// Round 4
// 111.708 us; speedup vs baseline: 7.0005x; 1.2093x over previous
//
#include <hip/hip_runtime.h>
#include <hip/hip_bf16.h>
#include <stdint.h>

#define S_LEN 4096
#define DIM   512
#define NH    8
#define HD    64
// 0.125 * log2(e): fold softmax base-2 conversion into the Q projection weights
#define QSCALE 0.18033688011112042f

typedef __attribute__((ext_vector_type(8))) short short8;
typedef __attribute__((ext_vector_type(4))) float f32x4;
typedef __attribute__((ext_vector_type(16))) float f32x16;
typedef __attribute__((ext_vector_type(2))) unsigned uint2v;

__device__ __forceinline__ uint32_t pk2(float lo, float hi) {
  union { __hip_bfloat162 h; uint32_t u; } cv;
  cv.h = __float22bfloat162_rn(float2{lo, hi});
  return cv.u;
}
__device__ __forceinline__ ushort bf1(float x) {
  union { __hip_bfloat16 b; ushort u; } cv;
  cv.b = __float2bfloat16(x);
  return cv.u;
}
__device__ __forceinline__ float bf2f(ushort u) {
  union { uint32_t u; float f; } cv;
  cv.u = (uint32_t)u << 16;
  return cv.f;
}

// ---------------- prep: x -> bf16 ----------------
__global__ __launch_bounds__(256)
void cast_x(const float* __restrict__ src, ushort* __restrict__ dst) {
  const int i = (blockIdx.x * 256 + threadIdx.x) * 8;
  const float4 a = *reinterpret_cast<const float4*>(src + i);
  const float4 b = *reinterpret_cast<const float4*>(src + i + 4);
  uint4 o;
  o.x = pk2(a.x, a.y); o.y = pk2(a.z, a.w);
  o.z = pk2(b.x, b.y); o.w = pk2(b.z, b.w);
  *reinterpret_cast<uint4*>(dst + i) = o;
}

// ---------------- prep: transpose weights to bf16 ----------------
__global__ __launch_bounds__(256)
void transpose_w(const float* __restrict__ qp, const float* __restrict__ kp,
                 const float* __restrict__ vp, const float* __restrict__ pp,
                 ushort* __restrict__ wbT, ushort* __restrict__ ppT) {
  __shared__ float L[64][65];
  const int z = blockIdx.z;
  const float* src = (z == 0) ? qp : (z == 1) ? kp : (z == 2) ? vp : pp;
  ushort* dst = (z < 3) ? (wbT + (size_t)z * 512 * 512) : ppT;
  const float scale = (z == 0) ? QSCALE : 1.0f;
  const int k0 = blockIdx.x * 64, n0 = blockIdx.y * 64;
  const int r = threadIdx.x >> 2, c0 = (threadIdx.x & 3) * 16;

#pragma unroll
  for (int j = 0; j < 4; ++j) {
    const float4 v =
        *reinterpret_cast<const float4*>(&src[(k0 + r) * 512 + n0 + c0 + 4 * j]);
    L[r][c0 + 4 * j + 0] = v.x * scale;
    L[r][c0 + 4 * j + 1] = v.y * scale;
    L[r][c0 + 4 * j + 2] = v.z * scale;
    L[r][c0 + 4 * j + 3] = v.w * scale;
  }
  __syncthreads();

  uint4 u0, u1;
  u0.x = pk2(L[c0 + 0][r], L[c0 + 1][r]);
  u0.y = pk2(L[c0 + 2][r], L[c0 + 3][r]);
  u0.z = pk2(L[c0 + 4][r], L[c0 + 5][r]);
  u0.w = pk2(L[c0 + 6][r], L[c0 + 7][r]);
  u1.x = pk2(L[c0 + 8][r], L[c0 + 9][r]);
  u1.y = pk2(L[c0 + 10][r], L[c0 + 11][r]);
  u1.z = pk2(L[c0 + 12][r], L[c0 + 13][r]);
  u1.w = pk2(L[c0 + 14][r], L[c0 + 15][r]);
  ushort* d = dst + (size_t)(n0 + r) * 512 + k0 + c0;
  *reinterpret_cast<uint4*>(d) = u0;
  *reinterpret_cast<uint4*>(d + 8) = u1;
}

// ---------------- bf16 MFMA GEMM ----------------
// MODE 0: qkv out. Q,K planes row-major [4096][64]; V plane TRANSPOSED [64][4096].
// MODE 1: f32 [M][512] out.
template <int MODE>
__global__ __launch_bounds__(256)
void gemm_bf16(const ushort* __restrict__ A, const ushort* __restrict__ Bt,
               void* __restrict__ Cout) {
  __shared__ __align__(16) unsigned char lds[24576];
  const int tid = threadIdx.x;
  const int m0 = blockIdx.x * 128, n0 = blockIdx.y * 64;
  const int lane = tid & 63, w = tid >> 6;
  const int wm = w >> 1, wn = w & 1;
  const int q = lane & 15, g = lane >> 4;
  f32x4 acc[4][2] = {};

  const int ar = tid >> 1, ah = tid & 1;
  const int br = tid >> 2, bq = tid & 3;

  for (int k0 = 0; k0 < 512; k0 += 64) {
    const ushort* ag = A + (size_t)(m0 + ar) * 512 + k0 + ah * 32;
    const uint4 a0 = *reinterpret_cast<const uint4*>(ag);
    const uint4 a1 = *reinterpret_cast<const uint4*>(ag + 8);
    const uint4 a2 = *reinterpret_cast<const uint4*>(ag + 16);
    const uint4 a3 = *reinterpret_cast<const uint4*>(ag + 24);
    const ushort* bg = Bt + (size_t)(n0 + br) * 512 + k0 + bq * 16;
    const uint4 b0 = *reinterpret_cast<const uint4*>(bg);
    const uint4 b1 = *reinterpret_cast<const uint4*>(bg + 8);
    __syncthreads();
    {
      unsigned char* ab = lds + ar * 128;
      const int asw = (ar & 7) << 4;
      *reinterpret_cast<uint4*>(ab + ((ah * 64 + 0) ^ asw)) = a0;
      *reinterpret_cast<uint4*>(ab + ((ah * 64 + 16) ^ asw)) = a1;
      *reinterpret_cast<uint4*>(ab + ((ah * 64 + 32) ^ asw)) = a2;
      *reinterpret_cast<uint4*>(ab + ((ah * 64 + 48) ^ asw)) = a3;
      unsigned char* bb = lds + 16384 + br * 128;
      const int bsw = (br & 7) << 4;
      *reinterpret_cast<uint4*>(bb + ((bq * 32 + 0) ^ bsw)) = b0;
      *reinterpret_cast<uint4*>(bb + ((bq * 32 + 16) ^ bsw)) = b1;
    }
    __syncthreads();

#pragma unroll
    for (int ks = 0; ks < 2; ++ks) {
      short8 bf[2];
#pragma unroll
      for (int ni = 0; ni < 2; ++ni) {
        const int rn = wn * 32 + ni * 16 + q;
        bf[ni] = *reinterpret_cast<const short8*>(
            lds + 16384 + rn * 128 + ((64 * ks + 16 * g) ^ ((rn & 7) << 4)));
      }
#pragma unroll
      for (int mi = 0; mi < 4; ++mi) {
        const int rm = wm * 64 + mi * 16 + q;
        const short8 af = *reinterpret_cast<const short8*>(
            lds + rm * 128 + ((64 * ks + 16 * g) ^ ((rm & 7) << 4)));
#pragma unroll
        for (int ni = 0; ni < 2; ++ni)
          acc[mi][ni] = __builtin_amdgcn_mfma_f32_16x16x32_bf16(
              af, bf[ni], acc[mi][ni], 0, 0, 0);
      }
    }
  }

  if (MODE == 0) {
    ushort* C = (ushort*)Cout;
    const int which = n0 >> 9;  // block-uniform
#pragma unroll
    for (int ni = 0; ni < 2; ++ni) {
      const int n = n0 + wn * 32 + ni * 16 + q;
      const int rem = n & 511, hh = rem >> 6, d = rem & 63;
      if (which == 2) {  // V transposed: [64 d][4096 s]
        ushort* base = C + (size_t)(2 * NH + hh) * (size_t)(S_LEN * HD) +
                       (size_t)d * S_LEN;
#pragma unroll
        for (int mi = 0; mi < 4; ++mi) {
          const int s = m0 + wm * 64 + mi * 16 + 4 * g;
          uint2 pw;
          pw.x = pk2(acc[mi][ni][0], acc[mi][ni][1]);
          pw.y = pk2(acc[mi][ni][2], acc[mi][ni][3]);
          *reinterpret_cast<uint2*>(base + s) = pw;
        }
      } else {
        ushort* base =
            C + ((size_t)which * NH + hh) * (size_t)(S_LEN * HD) + d;
#pragma unroll
        for (int mi = 0; mi < 4; ++mi) {
          const int s = m0 + wm * 64 + mi * 16 + 4 * g;
#pragma unroll
          for (int r = 0; r < 4; ++r)
            base[(size_t)(s + r) * HD] = bf1(acc[mi][ni][r]);
        }
      }
    }
  } else {
    float* C = (float*)Cout;
#pragma unroll
    for (int ni = 0; ni < 2; ++ni) {
      const int n = n0 + wn * 32 + ni * 16 + q;
#pragma unroll
      for (int mi = 0; mi < 4; ++mi) {
        const int s = m0 + wm * 64 + mi * 16 + 4 * g;
#pragma unroll
        for (int r = 0; r < 4; ++r)
          C[(size_t)(s + r) * 512 + n] = acc[mi][ni][r];
      }
    }
  }
}

// ---------------- MFMA flash attention, 32x32, KV-split-4 ----------------
// Block: 256 thr = 4 waves; wave w owns q rows qb*128 + w*32 .. +31.
// blockIdx.x = combo = z*8 + h (kv chunk z of head h); blockIdx.y = qb.
// S^T = K*Q^T (lane&31 = q col); O^T = V^T * P^T (lane&31 = q col too) so all
// softmax state is lane-local. P redistributed in-register via cvt_pk +
// permlane32_swap. Partials (unnormalized O^T, m, l) written to global;
// combine kernel merges the 4 chunks.
__global__ __launch_bounds__(256)
void attn_mfma32(const ushort* __restrict__ QKV, ushort* __restrict__ Opart,
                 float2* __restrict__ ML) {
  __shared__ __align__(16) unsigned char lds[16384];  // K 8K | Vt 8K
  const int tid = threadIdx.x;
  const int combo = blockIdx.x;
  const int h = combo & 7, z = combo >> 3;
  const int qb = blockIdx.y;
  const int lane = tid & 63, w = tid >> 6;
  const int r31 = lane & 31, hh = lane >> 5;

  const size_t plane = (size_t)S_LEN * HD;
  const ushort* Qp = QKV + (size_t)h * plane;
  const ushort* Kp = QKV + (size_t)(NH + h) * plane;       // [4096][64]
  const ushort* Vp = QKV + (size_t)(2 * NH + h) * plane;   // [64][4096]

  const int qrow = qb * 128 + w * 32 + r31;

  // Q fragments: qf[ks] = Q[qrow][16ks + 8hh .. +7]
  short8 qf[4];
  {
    const ushort* qptr = Qp + (size_t)qrow * HD + 8 * hh;
#pragma unroll
    for (int ks = 0; ks < 4; ++ks)
      qf[ks] = *reinterpret_cast<const short8*>(qptr + 16 * ks);
  }

  // per-(ks) swizzled fragment-read addresses (K at 0 / Vt at 8192, +4096/subtile)
  int raddr[4];
#pragma unroll
  for (int ks = 0; ks < 4; ++ks)
    raddr[ks] = r31 * 128 + (((2 * ks + hh) ^ (r31 & 7)) << 4);

  // staging: thread -> (row 0..63, 32B segment 0..3)
  const int trow = tid >> 2, seg = tid & 3;
  const int swr = (trow & 7) << 4;
  const int wk0 = trow * 128 + ((seg * 32) ^ swr);
  const int wk1 = trow * 128 + ((seg * 32 + 16) ^ swr);
  const ushort* kgbase = Kp + (size_t)(z * 1024 + trow) * HD + seg * 16;
  const ushort* vgbase = Vp + (size_t)trow * S_LEN + z * 1024 + seg * 16;

  f32x16 o[2] = {};
  float m_i = -1e30f, l_i = 0.f;

  uint4 kA = *reinterpret_cast<const uint4*>(kgbase);
  uint4 kB = *reinterpret_cast<const uint4*>(kgbase + 8);
  uint4 vA = *reinterpret_cast<const uint4*>(vgbase);
  uint4 vB = *reinterpret_cast<const uint4*>(vgbase + 8);

  for (int t = 0; t < 16; ++t) {
    __syncthreads();  // previous tile's fragment reads complete
    *reinterpret_cast<uint4*>(lds + wk0) = kA;
    *reinterpret_cast<uint4*>(lds + wk1) = kB;
    *reinterpret_cast<uint4*>(lds + 8192 + wk0) = vA;
    *reinterpret_cast<uint4*>(lds + 8192 + wk1) = vB;
    __syncthreads();

    // prefetch next tile (wraps on last iter; data unused)
    const int tn = (t + 1) & 15;
    kA = *reinterpret_cast<const uint4*>(kgbase + tn * 4096);
    kB = *reinterpret_cast<const uint4*>(kgbase + tn * 4096 + 8);
    vA = *reinterpret_cast<const uint4*>(vgbase + tn * 64);
    vB = *reinterpret_cast<const uint4*>(vgbase + tn * 64 + 8);

    // ---- S^T = K * Q^T  (two 32-row kpos subtiles) ----
    f32x16 s0 = {}, s1 = {};
#pragma unroll
    for (int ks = 0; ks < 4; ++ks) {
      const short8 a0 = *reinterpret_cast<const short8*>(lds + raddr[ks]);
      const short8 a1 = *reinterpret_cast<const short8*>(lds + raddr[ks] + 4096);
      s0 = __builtin_amdgcn_mfma_f32_32x32x16_bf16(a0, qf[ks], s0, 0, 0, 0);
      s1 = __builtin_amdgcn_mfma_f32_32x32x16_bf16(a1, qf[ks], s1, 0, 0, 0);
    }

    // ---- online softmax (base 2), deferred-max THR=8 ----
    float mv[8];
#pragma unroll
    for (int i = 0; i < 8; ++i)
      mv[i] = fmaxf(fmaxf(s0[i], s0[i + 8]), fmaxf(s1[i], s1[i + 8]));
#pragma unroll
    for (int i = 0; i < 4; ++i) mv[i] = fmaxf(mv[i], mv[i + 4]);
    float mx = fmaxf(fmaxf(mv[0], mv[1]), fmaxf(mv[2], mv[3]));
    mx = fmaxf(mx, __shfl_xor(mx, 32));

    const bool grow = mx > m_i + 8.0f;
    if (__any(grow)) {
      const float mn = grow ? mx : m_i;
      const float alpha = grow ? exp2f(m_i - mn) : 1.0f;
      l_i *= alpha;
#pragma unroll
      for (int i = 0; i < 16; ++i) { o[0][i] *= alpha; o[1][i] *= alpha; }
      m_i = mn;
    }

    float r0 = 0.f, r1 = 0.f, r2 = 0.f, r3 = 0.f;
#pragma unroll
    for (int i = 0; i < 16; i += 4) {
      s0[i + 0] = exp2f(s0[i + 0] - m_i); r0 += s0[i + 0];
      s0[i + 1] = exp2f(s0[i + 1] - m_i); r1 += s0[i + 1];
      s0[i + 2] = exp2f(s0[i + 2] - m_i); r2 += s0[i + 2];
      s0[i + 3] = exp2f(s0[i + 3] - m_i); r3 += s0[i + 3];
      s1[i + 0] = exp2f(s1[i + 0] - m_i); r0 += s1[i + 0];
      s1[i + 1] = exp2f(s1[i + 1] - m_i); r1 += s1[i + 1];
      s1[i + 2] = exp2f(s1[i + 2] - m_i); r2 += s1[i + 2];
      s1[i + 3] = exp2f(s1[i + 3] - m_i); r3 += s1[i + 3];
    }
    float rs = (r0 + r1) + (r2 + r3);
    rs += __shfl_xor(rs, 32);
    l_i += rs;

    // ---- P -> bf16 kpairs, redistribute across lane halves ----
    // u[mt][b][e] holds kpair 4b + 2hh + e of subtile mt.
    uint32_t u[2][4][2];
#pragma unroll
    for (int b = 0; b < 4; ++b)
#pragma unroll
      for (int e = 0; e < 2; ++e) {
        u[0][b][e] = pk2(s0[4 * b + 2 * e], s0[4 * b + 2 * e + 1]);
        u[1][b][e] = pk2(s1[4 * b + 2 * e], s1[4 * b + 2 * e + 1]);
      }
    short8 pf[4];
#pragma unroll
    for (int ks = 0; ks < 4; ++ks) {
      const int mt = ks >> 1, bb = 2 * (ks & 1);
      const uint2v se0 =
          __builtin_amdgcn_permlane32_swap(u[mt][bb][0], u[mt][bb + 1][0],
                                           false, false);
      const uint2v se1 =
          __builtin_amdgcn_permlane32_swap(u[mt][bb][1], u[mt][bb + 1][1],
                                           false, false);
      uint32_t fr[4] = {se0.x, se1.x, se0.y, se1.y};
      pf[ks] = *reinterpret_cast<short8*>(fr);
    }

    // ---- O^T += V^T * P^T ----
#pragma unroll
    for (int dt = 0; dt < 2; ++dt)
#pragma unroll
      for (int ks = 0; ks < 4; ++ks) {
        const short8 vf = *reinterpret_cast<const short8*>(
            lds + 8192 + dt * 4096 + raddr[ks]);
        o[dt] = __builtin_amdgcn_mfma_f32_32x32x16_bf16(vf, pf[ks], o[dt],
                                                        0, 0, 0);
      }
  }

  // ---- store partials ----
  if (lane < 32) ML[(size_t)combo * S_LEN + qrow] = float2{m_i, l_i};
  ushort* ob = Opart + (size_t)combo * 64 * S_LEN + qrow;
#pragma unroll
  for (int dt = 0; dt < 2; ++dt)
#pragma unroll
    for (int r = 0; r < 16; ++r) {
      const int d = 32 * dt + (r & 3) + 8 * (r >> 2) + 4 * hh;
      ob[(size_t)d * S_LEN] = bf1(o[dt][r]);
    }
}

// ---------------- combine the 4 kv-chunk partials ----------------
__global__ __launch_bounds__(256)
void combine(const ushort* __restrict__ Opart, const float2* __restrict__ ML,
             ushort* __restrict__ ob) {
  const int t = threadIdx.x;
  const int qq = t & 63, ds = t >> 6;
  const int q = blockIdx.x * 64 + qq;
  const int h = blockIdx.y;

  float m = -1e30f, mz[4], lz[4];
#pragma unroll
  for (int z = 0; z < 4; ++z) {
    const float2 v = ML[(size_t)(z * 8 + h) * S_LEN + q];
    mz[z] = v.x; lz[z] = v.y;
    m = fmaxf(m, v.x);
  }
  float wz[4], l = 0.f;
#pragma unroll
  for (int z = 0; z < 4; ++z) {
    wz[z] = exp2f(mz[z] - m);
    l += wz[z] * lz[z];
  }
  const float inv = 1.0f / l;

  float acc[16];
#pragma unroll
  for (int i = 0; i < 16; ++i) acc[i] = 0.f;
#pragma unroll
  for (int z = 0; z < 4; ++z) {
    const ushort* src =
        Opart + ((size_t)(z * 8 + h) * 64 + ds * 16) * S_LEN + q;
#pragma unroll
    for (int i = 0; i < 16; ++i)
      acc[i] += wz[z] * bf2f(src[(size_t)i * S_LEN]);
  }
  uint32_t pk[8];
#pragma unroll
  for (int i = 0; i < 8; ++i)
    pk[i] = pk2(acc[2 * i] * inv, acc[2 * i + 1] * inv);
  ushort* dst = ob + (size_t)q * DIM + h * 64 + ds * 16;
  *reinterpret_cast<uint4*>(dst) = *reinterpret_cast<uint4*>(pk);
  *reinterpret_cast<uint4*>(dst + 8) = *reinterpret_cast<uint4*>(pk + 4);
}

extern "C" void kernel_launch(void* const* d_in, const int* in_sizes, int n_in,
                              void* d_out, int out_size, void* d_ws, size_t ws_size,
                              hipStream_t stream) {
  const float* x  = (const float*)d_in[0];
  const float* qp = (const float*)d_in[1];
  const float* kp = (const float*)d_in[2];
  const float* vp = (const float*)d_in[3];
  const float* pp = (const float*)d_in[4];
  float* out = (float*)d_out;

  unsigned char* ws = (unsigned char*)d_ws;
  ushort* xb    = (ushort*)(ws);                       // 4 MB
  ushort* qkvb  = (ushort*)(ws + ((size_t)4 << 20));   // 12 MB [3][8] planes
  ushort* ob    = (ushort*)(ws + ((size_t)16 << 20));  // 4 MB [4096][512]
  ushort* wbT   = (ushort*)(ws + ((size_t)20 << 20));  // 1.5 MB
  ushort* ppT   = (ushort*)(ws + ((size_t)22 << 20));  // 0.5 MB
  ushort* opart = (ushort*)(ws + ((size_t)23 << 20));  // 16 MB [32][64][4096]
  float2* ml    = (float2*)(ws + ((size_t)39 << 20));  // 1 MB [32][4096]

  cast_x<<<dim3(1024), dim3(256), 0, stream>>>(x, xb);
  transpose_w<<<dim3(8, 8, 4), dim3(256), 0, stream>>>(qp, kp, vp, pp, wbT, ppT);
  gemm_bf16<0><<<dim3(32, 24), dim3(256), 0, stream>>>(xb, wbT, qkvb);
  attn_mfma32<<<dim3(32, 32), dim3(256), 0, stream>>>(qkvb, opart, ml);
  combine<<<dim3(64, 8), dim3(256), 0, stream>>>(opart, ml, ob);
  gemm_bf16<1><<<dim3(32, 8), dim3(256), 0, stream>>>(ob, ppT, out);
}